// Round 6
// baseline (134.565 us; speedup 1.0000x reference)
//
#include <hip/hip_runtime.h>
#include <math.h>

#define NB 4096
#define NN 10000
#define ND 256
#define ND4 (ND / 4)          // 64 float4 per row
#define ALPHA 0.2f
#define CS 16                 // rows per chunk
#define NG (NN / CS)          // 625 chunks (exact)
#define SCHUNK 25             // chunks per superchunk
#define NSUPER (NG / SCHUNK)  // 25 superchunks (exact)
#define NTILES 40             // 40*256 >= 10000
#define MSEGS 26
#define SEGLEN ((NN + MSEGS - 1) / MSEGS)   // 385
#define CHUNK_BLOCKS ((NG + 3) / 4)         // 157 (4 chunks per 256-block)
// zero region: rank[NN] + ntdone[NTILES] + SSA/SSC[2*NSUPER*ND] + ssa0/ssc0[2*NSUPER]
#define ZELEMS (NN + NTILES + 2 * NSUPER * ND + 2 * NSUPER)

typedef unsigned long long u64;

// --- 1) dots t_n=V[n]·Wn, s_b=P[b]·Wp (one wave/row); strict-total-order u64
// keys tk[n]; zero the atomic-accumulator region.
__global__ __launch_bounds__(256) void k_dot(
    const float* __restrict__ P, const float* __restrict__ V,
    const float* __restrict__ K,
    float* __restrict__ t, float* __restrict__ s, u64* __restrict__ tk,
    int* __restrict__ zero_region) {
  int gt = blockIdx.x * 256 + threadIdx.x;
  if (gt < ZELEMS) zero_region[gt] = 0;
  int j = blockIdx.x * 4 + (threadIdx.x >> 6);
  int lane = threadIdx.x & 63;
  if (j >= NN + NB) return;
  const float* row; const float* wv; int oi; bool isn;
  if (j < NN) { row = V + (size_t)j * ND; wv = K + ND; oi = j; isn = true; }
  else        { row = P + (size_t)(j - NN) * ND; wv = K; oi = j - NN; isn = false; }
  float4 r  = ((const float4*)row)[lane];
  float4 kx = ((const float4*)wv)[lane];
  float acc = r.x * kx.x + r.y * kx.y + r.z * kx.z + r.w * kx.w;
  #pragma unroll
  for (int off = 32; off; off >>= 1) acc += __shfl_down(acc, off, 64);
  if (lane == 0) {
    if (isn) {
      t[oi] = acc;
      unsigned bits = __float_as_uint(acc);
      unsigned key = bits ^ (((int)bits >> 31) | 0x80000000u);  // monotone map
      tk[oi] = ((u64)key << 14) | (unsigned)oi;
    } else {
      s[oi] = acc;
    }
  }
}

// --- 2) rank + (winner-block) scatter. Grid (NTILES, MSEGS).
// Each block: partial rank of its 256 n's over m-segment [m0,m1) via
// wave-uniform key loads; atomicAdd into rank[]. Then ACQ_REL inc of
// ntdone[ntile]; the 26th arriver sees all adds (release->acquire chain),
// re-reads final ranks coherently and scatters tsort/eA/eC/idxs.
__global__ __launch_bounds__(256) void k_rank_scatter(
    const u64* __restrict__ tk, const float* __restrict__ t,
    int* __restrict__ rank, int* __restrict__ ntdone,
    float* __restrict__ tsort, float* __restrict__ eA, float* __restrict__ eC,
    int* __restrict__ idxs) {
  int ntile = blockIdx.x, seg = blockIdx.y;
  int n = ntile * 256 + threadIdx.x;
  u64 kn = (n < NN) ? tk[n] : ~0ull;
  int m0 = seg * SEGLEN, m1 = min(NN, m0 + SEGLEN);
  int r = 0;
  int m = m0;
  #pragma unroll 1
  for (; m + 4 <= m1; m += 4) {
    u64 a = tk[m], b2 = tk[m + 1], c = tk[m + 2], dd = tk[m + 3];
    r += (a < kn) + (b2 < kn) + (c < kn) + (dd < kn);
  }
  for (; m < m1; ++m) r += (tk[m] < kn);
  if (n < NN && r) atomicAdd(&rank[n], r);
  __syncthreads();                    // drains the adds (barrier waitcnt)
  __shared__ int who;
  if (threadIdx.x == 0)
    who = __hip_atomic_fetch_add(&ntdone[ntile], 1, __ATOMIC_ACQ_REL,
                                 __HIP_MEMORY_SCOPE_AGENT);
  __syncthreads();
  if (who == MSEGS - 1 && n < NN) {
    int rr = __hip_atomic_load(&rank[n], __ATOMIC_RELAXED,
                               __HIP_MEMORY_SCOPE_AGENT);
    float tn = t[n];
    tsort[rr] = tn;
    eA[rr] = __expf(tn);
    eC[rr] = __expf(ALPHA * tn);
    idxs[rr] = n;
  }
}

// --- 3) blocks <CHUNK_BLOCKS: one wave per chunk (64 lanes x float4 = 256
// cols): chunk sums + atomic superchunk sums. Tail blocks: binary searches.
__global__ __launch_bounds__(256) void k_chunk(
    const float* __restrict__ eA, const float* __restrict__ eC,
    const int* __restrict__ idxs, const float* __restrict__ V,
    const float* __restrict__ s, const float* __restrict__ tsort,
    float* __restrict__ SA, float* __restrict__ SC,
    float* __restrict__ sa0, float* __restrict__ sc0,
    float* __restrict__ SSA, float* __restrict__ SSC,
    float* __restrict__ ssa0, float* __restrict__ ssc0,
    int* __restrict__ kk) {
  int bid = blockIdx.x, tid = threadIdx.x;
  if (bid < CHUNK_BLOCKS) {
    int g = bid * 4 + (tid >> 6);
    if (g >= NG) return;
    int lane = tid & 63;
    const float4* V4 = (const float4*)V;
    float4 aA = {0.f, 0.f, 0.f, 0.f}, aC = {0.f, 0.f, 0.f, 0.f};
    float sa = 0.f, sc = 0.f;
    int base = g * CS;
    #pragma unroll
    for (int j = 0; j < CS; ++j) {
      int i = base + j;
      float ea = eA[i], ec = eC[i];       // wave-uniform -> scalar loads
      int id = idxs[i];
      float4 v = V4[(size_t)id * ND4 + lane];
      aA.x += ea * v.x; aA.y += ea * v.y; aA.z += ea * v.z; aA.w += ea * v.w;
      aC.x += ec * v.x; aC.y += ec * v.y; aC.z += ec * v.z; aC.w += ec * v.w;
      sa += ea; sc += ec;
    }
    ((float4*)SA)[(size_t)g * ND4 + lane] = aA;
    ((float4*)SC)[(size_t)g * ND4 + lane] = aC;
    int gs = g / SCHUNK;
    float* pA = &SSA[(size_t)gs * ND + lane * 4];
    float* pC = &SSC[(size_t)gs * ND + lane * 4];
    atomicAdd(pA + 0, aA.x); atomicAdd(pA + 1, aA.y);
    atomicAdd(pA + 2, aA.z); atomicAdd(pA + 3, aA.w);
    atomicAdd(pC + 0, aC.x); atomicAdd(pC + 1, aC.y);
    atomicAdd(pC + 2, aC.z); atomicAdd(pC + 3, aC.w);
    if (lane == 0) {
      sa0[g] = sa; sc0[g] = sc;
      atomicAdd(&ssa0[gs], sa);
      atomicAdd(&ssc0[gs], sc);
    }
  } else {
    int b = (bid - CHUNK_BLOCKS) * 256 + tid;   // 16 blocks x 256 = 4096
    if (b < NB) {
      float key = -s[b];
      int lo = 0, hi = NN;   // lower_bound: first idx with tsort[idx] >= key
      while (lo < hi) {
        int mid = (lo + hi) >> 1;
        if (tsort[mid] < key) lo = mid + 1; else hi = mid;
      }
      kk[b] = lo;
    }
  }
}

// --- 4) finalize: one wave per patient (64 lanes x float4). A-side suffix,
// C-side prefix: 25 SS rows + <=24 chunk rows + <=15 V rows, fused epilogue.
__global__ __launch_bounds__(256) void k_finalize(
    const float* __restrict__ P, const float* __restrict__ V,
    const float* __restrict__ s, const int* __restrict__ kk,
    const float* __restrict__ eA, const float* __restrict__ eC,
    const int* __restrict__ idxs,
    const float* __restrict__ SA, const float* __restrict__ SC,
    const float* __restrict__ sa0, const float* __restrict__ sc0,
    const float* __restrict__ SSA, const float* __restrict__ SSC,
    const float* __restrict__ ssa0, const float* __restrict__ ssc0,
    float* __restrict__ out) {
  int b = blockIdx.x * 4 + (threadIdx.x >> 6);   // grid NB/4
  int lane = threadIdx.x & 63;
  int k = kk[b];
  int g = k >> 4;          // chunk idx; k==NN -> g==NG
  int gs = g / SCHUNK;     // superchunk idx; g==NG -> gs==NSUPER
  const float4* SSA4 = (const float4*)SSA;
  const float4* SSC4 = (const float4*)SSC;
  const float4* SA4  = (const float4*)SA;
  const float4* SC4  = (const float4*)SC;
  const float4* V4   = (const float4*)V;
  float4 sA = {0.f, 0.f, 0.f, 0.f}, pC = {0.f, 0.f, 0.f, 0.f};
  float suffa = 0.f, prefc = 0.f;
  for (int q = gs; q < NSUPER; ++q) {
    float4 v = SSA4[(size_t)q * ND4 + lane];
    sA.x += v.x; sA.y += v.y; sA.z += v.z; sA.w += v.w;
    suffa += ssa0[q];
  }
  for (int q = 0; q < gs; ++q) {
    float4 v = SSC4[(size_t)q * ND4 + lane];
    pC.x += v.x; pC.y += v.y; pC.z += v.z; pC.w += v.w;
    prefc += ssc0[q];
  }
  for (int j = gs * SCHUNK; j < g; ++j) {
    float4 a = SA4[(size_t)j * ND4 + lane];
    float4 c = SC4[(size_t)j * ND4 + lane];
    sA.x -= a.x; sA.y -= a.y; sA.z -= a.z; sA.w -= a.w;
    pC.x += c.x; pC.y += c.y; pC.z += c.z; pC.w += c.w;
    suffa -= sa0[j]; prefc += sc0[j];
  }
  for (int i = g << 4; i < k; ++i) {
    float ea = eA[i], ec = eC[i];
    float4 v = V4[(size_t)idxs[i] * ND4 + lane];
    sA.x -= ea * v.x; sA.y -= ea * v.y; sA.z -= ea * v.z; sA.w -= ea * v.w;
    pC.x += ec * v.x; pC.y += ec * v.y; pC.z += ec * v.z; pC.w += ec * v.w;
    suffa -= ea; prefc += ec;
  }
  float sb = s[b];
  float ea = __expf(sb), ec = __expf(ALPHA * sb);
  float inv = 1.f / (ea * suffa + ec * prefc);
  float4 p = ((const float4*)P)[(size_t)b * ND4 + lane];
  float4 o;
  o.x = p.x + (ea * sA.x + ec * pC.x) * inv;
  o.y = p.y + (ea * sA.y + ec * pC.y) * inv;
  o.z = p.z + (ea * sA.z + ec * pC.z) * inv;
  o.w = p.w + (ea * sA.w + ec * pC.w) * inv;
  ((float4*)out)[(size_t)b * ND4 + lane] = o;
}

extern "C" void kernel_launch(void* const* d_in, const int* in_sizes, int n_in,
                              void* d_out, int out_size, void* d_ws, size_t ws_size,
                              hipStream_t stream) {
  const float* P = (const float*)d_in[0];   // (B, D)
  const float* V = (const float*)d_in[1];   // (N, D)
  const float* K = (const float*)d_in[2];   // (2D, 1)
  float* out = (float*)d_out;

  char* w = (char*)d_ws;
  u64*   tk    = (u64*)w;   w += sizeof(u64) * NN;        // 8B-aligned first
  // --- zeroed-by-k_dot region (contiguous) ---
  int*   zreg  = (int*)w;
  int*   rank  = (int*)w;   w += sizeof(int) * NN;
  int*   ntdone= (int*)w;   w += sizeof(int) * NTILES;
  float* SSA   = (float*)w; w += sizeof(float) * NSUPER * ND;
  float* SSC   = (float*)w; w += sizeof(float) * NSUPER * ND;
  float* ssa0  = (float*)w; w += sizeof(float) * NSUPER;
  float* ssc0  = (float*)w; w += sizeof(float) * NSUPER;
  // --- rest ---
  float* t     = (float*)w; w += sizeof(float) * NN;
  float* s     = (float*)w; w += sizeof(float) * NB;
  float* tsort = (float*)w; w += sizeof(float) * NN;
  float* eA    = (float*)w; w += sizeof(float) * NN;
  float* eC    = (float*)w; w += sizeof(float) * NN;
  int*   idxs  = (int*)w;   w += sizeof(int) * NN;
  int*   kk    = (int*)w;   w += sizeof(int) * NB;
  float* SA    = (float*)w; w += sizeof(float) * (size_t)NG * ND;
  float* SC    = (float*)w; w += sizeof(float) * (size_t)NG * ND;
  float* sa0   = (float*)w; w += sizeof(float) * NG;
  float* sc0   = (float*)w; w += sizeof(float) * NG;

  k_dot<<<(NN + NB + 3) / 4, 256, 0, stream>>>(P, V, K, t, s, tk, zreg);
  k_rank_scatter<<<dim3(NTILES, MSEGS), 256, 0, stream>>>(
      tk, t, rank, ntdone, tsort, eA, eC, idxs);
  k_chunk<<<CHUNK_BLOCKS + NB / 256, 256, 0, stream>>>(
      eA, eC, idxs, V, s, tsort, SA, SC, sa0, sc0, SSA, SSC, ssa0, ssc0, kk);
  k_finalize<<<NB / 4, 256, 0, stream>>>(
      P, V, s, kk, eA, eC, idxs, SA, SC, sa0, sc0, SSA, SSC, ssa0, ssc0, out);
}